// Round 2
// baseline (478.310 us; speedup 1.0000x reference)
//
#include <hip/hip_runtime.h>

// Problem constants (fixed by the reference).
#define BB 32
#define KK 8192
#define EE 128
#define HH 128
#define CH 32                     // K-chunks per batch -> 1024 blocks = 2 blocks/CU
#define TPB (KK / CH)             // 256 tokens per block
#define STRIP 32                  // tokens per LDS strip
#define NSTRIP (TPB / STRIP)      // 8
#define ZSTR 136                  // LDS row stride in shorts (272 B, 16B-aligned)

typedef short bf16x8 __attribute__((ext_vector_type(8)));
typedef float f32x4  __attribute__((ext_vector_type(4)));

static __device__ __forceinline__ unsigned short f2bf(float x) {
    union { float f; unsigned u; } v; v.f = x;
    unsigned u = v.u;
    u += 0x7FFFu + ((u >> 16) & 1u);   // RNE
    return (unsigned short)(u >> 16);
}

static __device__ __forceinline__ ushort4 cvt4(float4 v) {
    ushort4 o;
    o.x = f2bf(v.x); o.y = f2bf(v.y); o.z = f2bf(v.z); o.w = f2bf(v.w);
    return o;
}

// Load 8 contiguous fp32 -> bf16 MFMA fragment (16 B).
static __device__ __forceinline__ bf16x8 load8_bf16(const float* __restrict__ p) {
    const float4 a = ((const float4*)p)[0];
    const float4 b = ((const float4*)p)[1];
    bf16x8 r;
    r[0] = (short)f2bf(a.x); r[1] = (short)f2bf(a.y);
    r[2] = (short)f2bf(a.z); r[3] = (short)f2bf(a.w);
    r[4] = (short)f2bf(b.x); r[5] = (short)f2bf(b.y);
    r[6] = (short)f2bf(b.z); r[7] = (short)f2bf(b.w);
    return r;
}

// ---------------------------------------------------------------------------
// Phase 1: per-chunk partial column-max of z @ M2^T (bias added in reduce).
// 1024 blocks x 512 threads (8 waves, one 16-feature tile each).
// D = M2 . z^T  (transposed C: lane holds 4 consecutive features, 1 token)
// ---------------------------------------------------------------------------
__global__ __launch_bounds__(512, 4)
void pool_partial(const float* __restrict__ z, const float* __restrict__ M2w,
                  float* __restrict__ part) {
    __shared__ unsigned short zl[2][STRIP * ZSTR];

    const int tid  = threadIdx.x;
    const int fq   = tid >> 6, lane = tid & 63, q = lane >> 4, l16 = lane & 15;
    const int blk  = blockIdx.x;
    const int b    = blk >> 5, ch = blk & (CH - 1);
    const long tok0 = (long)b * KK + (long)ch * TPB;

    const int srow = tid >> 5;      // staging row (0..15), +16 for i=1
    const int sc4  = tid & 31;      // staging float4 col

    // M2 weight A-fragments in registers (f = fq*16 + l16 rows).
    bf16x8 wf[4];
    for (int k = 0; k < 4; ++k)
        wf[k] = load8_bf16(M2w + (fq * 16 + l16) * EE + k * 32 + q * 8);

    // stage strip 0
    {
        float4 R[2];
        for (int i = 0; i < 2; ++i)
            R[i] = ((const float4*)(z + (tok0 + i * 16 + srow) * EE))[sc4];
        for (int i = 0; i < 2; ++i)
            *(ushort4*)&zl[0][(i * 16 + srow) * ZSTR + sc4 * 4] = cvt4(R[i]);
    }
    __syncthreads();

    f32x4 rmax[2];
    for (int t = 0; t < 2; ++t)
        for (int r = 0; r < 4; ++r) rmax[t][r] = -3.0e38f;

    for (int s = 0; s < NSTRIP; ++s) {
        const int p = s & 1;
        const bool pf = (s + 1 < NSTRIP);
        float4 R[2];
        if (pf)
            for (int i = 0; i < 2; ++i)
                R[i] = ((const float4*)(z + (tok0 + (s + 1) * STRIP + i * 16 + srow) * EE))[sc4];

        for (int ts = 0; ts < 2; ++ts) {
            f32x4 acc = {0.f, 0.f, 0.f, 0.f};
            for (int k = 0; k < 4; ++k) {
                const bf16x8 zf = *(const bf16x8*)&zl[p][(ts * 16 + l16) * ZSTR + k * 32 + q * 8];
                acc = __builtin_amdgcn_mfma_f32_16x16x32_bf16(wf[k], zf, acc, 0, 0, 0);
            }
            for (int r = 0; r < 4; ++r)
                rmax[ts][r] = fmaxf(rmax[ts][r], acc[r]);
        }

        if (pf)
            for (int i = 0; i < 2; ++i)
                *(ushort4*)&zl[1 - p][(i * 16 + srow) * ZSTR + sc4 * 4] = cvt4(R[i]);
        __syncthreads();
    }

    // combine token sub-tiles, then reduce across the 16 token-lanes (l16)
    f32x4 rm;
    for (int r = 0; r < 4; ++r) rm[r] = fmaxf(rmax[0][r], rmax[1][r]);
    for (int off = 1; off < 16; off <<= 1)
        for (int r = 0; r < 4; ++r)
            rm[r] = fmaxf(rm[r], __shfl_xor(rm[r], off, 64));
    if (l16 == 0) {
        float4 o; o.x = rm[0]; o.y = rm[1]; o.z = rm[2]; o.w = rm[3];
        *(float4*)(part + (size_t)blk * EE + fq * 16 + q * 4) = o;
    }
}

// ---------------------------------------------------------------------------
// Phase 1b: reduce partials over chunks, add M2 bias. grid = B, block = 128.
// ---------------------------------------------------------------------------
__global__ void pool_reduce(const float* __restrict__ part,
                            const float* __restrict__ M2b,
                            float* __restrict__ pooled) {
    const int b = blockIdx.x, f = threadIdx.x;
    float m = -3.0e38f;
    for (int ch = 0; ch < CH; ++ch)
        m = fmaxf(m, part[((size_t)(b * CH + ch)) * EE + f]);
    pooled[b * EE + f] = m + M2b[f];
}

// ---------------------------------------------------------------------------
// Phase 2: out = relu([z | relu(z@M1^T + b1 + pooled)] @ U^T + bU)
// 1024 blocks x 512 threads (8 waves, one 16-h tile each). Transposed MFMA:
// step1 D = M1.z^T -> ml tile; step2 D = U.[z|m]^T -> float4 stores.
// ---------------------------------------------------------------------------
__global__ __launch_bounds__(512, 4)
void fused_main(const float* __restrict__ z,  const float* __restrict__ M1w,
                const float* __restrict__ M1b, const float* __restrict__ Uw,
                const float* __restrict__ Ub,  const float* __restrict__ pooled,
                float* __restrict__ out) {
    __shared__ unsigned short zl[2][STRIP * ZSTR];
    __shared__ unsigned short ml[2][STRIP * ZSTR];

    const int tid  = threadIdx.x;
    const int fq   = tid >> 6, lane = tid & 63, q = lane >> 4, l16 = lane & 15;
    const int blk  = blockIdx.x;
    const int b    = blk >> 5, ch = blk & (CH - 1);
    const long tok0 = (long)b * KK + (long)ch * TPB;

    const int srow = tid >> 5;
    const int sc4  = tid & 31;

    // M1 / U weight A-fragments (row = fq*16 + l16).
    bf16x8 wf1[4];
    for (int k = 0; k < 4; ++k)
        wf1[k] = load8_bf16(M1w + (fq * 16 + l16) * EE + k * 32 + q * 8);
    bf16x8 wfu[8];
    for (int kk = 0; kk < 8; ++kk)
        wfu[kk] = load8_bf16(Uw + (fq * 16 + l16) * (2 * EE) + kk * 32 + q * 8);

    // per-lane biases: rows of the C tile are 4 consecutive features/h.
    const float4 mb = *(const float4*)(M1b + fq * 16 + q * 4);
    const float4 pl = *(const float4*)(pooled + b * EE + fq * 16 + q * 4);
    float4 bp; bp.x = mb.x + pl.x; bp.y = mb.y + pl.y;
              bp.z = mb.z + pl.z; bp.w = mb.w + pl.w;
    const float4 ub = *(const float4*)(Ub + fq * 16 + q * 4);

    // stage strip 0
    {
        float4 R[2];
        for (int i = 0; i < 2; ++i)
            R[i] = ((const float4*)(z + (tok0 + i * 16 + srow) * EE))[sc4];
        for (int i = 0; i < 2; ++i)
            *(ushort4*)&zl[0][(i * 16 + srow) * ZSTR + sc4 * 4] = cvt4(R[i]);
    }
    __syncthreads();

    for (int s = 0; s < NSTRIP; ++s) {
        const int p = s & 1;
        const bool pf = (s + 1 < NSTRIP);
        float4 R[2];
        if (pf)
            for (int i = 0; i < 2; ++i)
                R[i] = ((const float4*)(z + (tok0 + (s + 1) * STRIP + i * 16 + srow) * EE))[sc4];

        // step 1: m-tile = relu(M1 . z^T + bp) -> bf16 LDS (rows=f, transposed C)
        for (int ts = 0; ts < 2; ++ts) {
            f32x4 a = {0.f, 0.f, 0.f, 0.f};
            for (int k = 0; k < 4; ++k) {
                const bf16x8 zf = *(const bf16x8*)&zl[p][(ts * 16 + l16) * ZSTR + k * 32 + q * 8];
                a = __builtin_amdgcn_mfma_f32_16x16x32_bf16(wf1[k], zf, a, 0, 0, 0);
            }
            ushort4 o;
            o.x = f2bf(fmaxf(a[0] + bp.x, 0.f));
            o.y = f2bf(fmaxf(a[1] + bp.y, 0.f));
            o.z = f2bf(fmaxf(a[2] + bp.z, 0.f));
            o.w = f2bf(fmaxf(a[3] + bp.w, 0.f));
            *(ushort4*)&ml[p][(ts * 16 + l16) * ZSTR + fq * 16 + q * 4] = o;
        }
        __syncthreads();   // ml[p] ready

        // step 2: out-tile = relu(U . [z|m]^T + ub) -> float4 stores
        for (int ts = 0; ts < 2; ++ts) {
            f32x4 a = {0.f, 0.f, 0.f, 0.f};
            for (int kk = 0; kk < 4; ++kk) {
                const bf16x8 zf = *(const bf16x8*)&zl[p][(ts * 16 + l16) * ZSTR + kk * 32 + q * 8];
                a = __builtin_amdgcn_mfma_f32_16x16x32_bf16(wfu[kk], zf, a, 0, 0, 0);
            }
            for (int kk = 0; kk < 4; ++kk) {
                const bf16x8 mf = *(const bf16x8*)&ml[p][(ts * 16 + l16) * ZSTR + kk * 32 + q * 8];
                a = __builtin_amdgcn_mfma_f32_16x16x32_bf16(wfu[4 + kk], mf, a, 0, 0, 0);
            }
            float4 o;
            o.x = fmaxf(a[0] + ub.x, 0.f);
            o.y = fmaxf(a[1] + ub.y, 0.f);
            o.z = fmaxf(a[2] + ub.z, 0.f);
            o.w = fmaxf(a[3] + ub.w, 0.f);
            *(float4*)(out + (tok0 + s * STRIP + ts * 16 + l16) * HH + fq * 16 + q * 4) = o;
        }

        if (pf)
            for (int i = 0; i < 2; ++i)
                *(ushort4*)&zl[1 - p][(i * 16 + srow) * ZSTR + sc4 * 4] = cvt4(R[i]);
        __syncthreads();   // zl[1-p] ready; all step2 reads of zl[p]/ml[p] done
    }
}

// ---------------------------------------------------------------------------
extern "C" void kernel_launch(void* const* d_in, const int* in_sizes, int n_in,
                              void* d_out, int out_size, void* d_ws, size_t ws_size,
                              hipStream_t stream) {
    const float* z   = (const float*)d_in[0];
    const float* M1w = (const float*)d_in[1];
    const float* M1b = (const float*)d_in[2];
    const float* M2w = (const float*)d_in[3];
    const float* M2b = (const float*)d_in[4];
    const float* Uw  = (const float*)d_in[5];
    const float* Ub  = (const float*)d_in[6];
    float* out = (float*)d_out;

    // workspace: [0, B*CH*E) partial maxes (512 KB), then [.., +B*E) pooled
    float* part   = (float*)d_ws;
    float* pooled = part + (size_t)BB * CH * EE;

    hipLaunchKernelGGL(pool_partial, dim3(BB * CH), dim3(512), 0, stream, z, M2w, part);
    hipLaunchKernelGGL(pool_reduce,  dim3(BB),      dim3(EE),  0, stream, part, M2b, pooled);
    hipLaunchKernelGGL(fused_main,   dim3(BB * CH), dim3(512), 0, stream,
                       z, M1w, M1b, Uw, Ub, pooled, out);
}

// Round 3
// 410.824 us; speedup vs baseline: 1.1643x; 1.1643x over previous
//
#include <hip/hip_runtime.h>

// Problem constants (fixed by the reference).
#define BB 32
#define KK 8192
#define EE 128
#define HH 128
#define CH 32                     // chunks per batch -> 1024 blocks
#define TPB (KK / CH)             // 256 tokens per block
#define STRIP 32                  // tokens per LDS strip
#define NSTRIP (TPB / STRIP)      // 8
#define ZSTR 136                  // LDS row stride in shorts (272 B, 16B-aligned)

typedef short bf16x8 __attribute__((ext_vector_type(8)));
typedef float f32x4  __attribute__((ext_vector_type(4)));

static __device__ __forceinline__ unsigned short f2bf(float x) {
    union { float f; unsigned u; } v; v.f = x;
    unsigned u = v.u;
    u += 0x7FFFu + ((u >> 16) & 1u);   // RNE
    return (unsigned short)(u >> 16);
}

static __device__ __forceinline__ bf16x8 cvt8(float4 a, float4 b) {
    bf16x8 r;
    r[0] = (short)f2bf(a.x); r[1] = (short)f2bf(a.y);
    r[2] = (short)f2bf(a.z); r[3] = (short)f2bf(a.w);
    r[4] = (short)f2bf(b.x); r[5] = (short)f2bf(b.y);
    r[6] = (short)f2bf(b.z); r[7] = (short)f2bf(b.w);
    return r;
}

static __device__ __forceinline__ bf16x8 load8_bf16(const float* __restrict__ p) {
    return cvt8(((const float4*)p)[0], ((const float4*)p)[1]);
}

// ---------------------------------------------------------------------------
// Phase 1: partial column-max of z @ M2^T; also emits z as bf16 (zb) if the
// workspace is big enough. 1024 blocks x 256 threads (4 waves, 2 tiles/wave).
// MFMA computes D = M2 . z^T (lane holds 4 consecutive f for one token).
// ---------------------------------------------------------------------------
__global__ __launch_bounds__(256, 4)
void pool_partial(const float* __restrict__ z, const float* __restrict__ M2w,
                  float* __restrict__ part, unsigned short* __restrict__ zb,
                  int write_zb) {
    __shared__ __attribute__((aligned(16))) unsigned short zl[2][STRIP * ZSTR];

    const int tid  = threadIdx.x;
    const int w    = tid >> 6, lane = tid & 63, q = lane >> 4, l16 = lane & 15;
    const int blk  = blockIdx.x;
    const int b    = blk >> 5, ch = blk & (CH - 1);
    const long tok0 = (long)b * KK + (long)ch * TPB;

    // staging map: thread covers rows srow and srow+16, 8-float group spr
    const int srow = tid >> 4;     // 0..15
    const int spr  = tid & 15;     // 0..15

    // M2 weight A-fragments: wave owns features w*32 .. w*32+31 (2 tiles)
    bf16x8 wf[2][4];
    for (int t = 0; t < 2; ++t)
        for (int k = 0; k < 4; ++k)
            wf[t][k] = load8_bf16(M2w + (w * 32 + t * 16 + l16) * EE + k * 32 + q * 8);

    // stage strip 0 (and emit zb)
    {
        const float* r0 = z + (tok0 + srow) * EE + spr * 8;
        const float* r1 = z + (tok0 + 16 + srow) * EE + spr * 8;
        bf16x8 c0 = cvt8(((const float4*)r0)[0], ((const float4*)r0)[1]);
        bf16x8 c1 = cvt8(((const float4*)r1)[0], ((const float4*)r1)[1]);
        *(bf16x8*)&zl[0][srow * ZSTR + spr * 8] = c0;
        *(bf16x8*)&zl[0][(16 + srow) * ZSTR + spr * 8] = c1;
        if (write_zb) {
            *(bf16x8*)(zb + (tok0 + srow) * EE + spr * 8) = c0;
            *(bf16x8*)(zb + (tok0 + 16 + srow) * EE + spr * 8) = c1;
        }
    }
    __syncthreads();

    f32x4 rmax[2];
    for (int t = 0; t < 2; ++t)
        for (int r = 0; r < 4; ++r) rmax[t][r] = -3.0e38f;

    for (int s = 0; s < NSTRIP; ++s) {
        const int p = s & 1;
        const bool pf = (s + 1 < NSTRIP);
        float4 A0, A1, B0, B1;
        if (pf) {
            const float* r0 = z + (tok0 + (s + 1) * STRIP + srow) * EE + spr * 8;
            const float* r1 = z + (tok0 + (s + 1) * STRIP + 16 + srow) * EE + spr * 8;
            A0 = ((const float4*)r0)[0]; A1 = ((const float4*)r0)[1];
            B0 = ((const float4*)r1)[0]; B1 = ((const float4*)r1)[1];
        }

        for (int ts = 0; ts < 2; ++ts) {
            bf16x8 zf[4];
            for (int k = 0; k < 4; ++k)
                zf[k] = *(const bf16x8*)&zl[p][(ts * 16 + l16) * ZSTR + k * 32 + q * 8];
            f32x4 acc[2] = {};
            for (int k = 0; k < 4; ++k)
                for (int t = 0; t < 2; ++t)
                    acc[t] = __builtin_amdgcn_mfma_f32_16x16x32_bf16(wf[t][k], zf[k], acc[t], 0, 0, 0);
            for (int t = 0; t < 2; ++t)
                for (int r = 0; r < 4; ++r)
                    rmax[t][r] = fmaxf(rmax[t][r], acc[t][r]);
        }

        if (pf) {
            bf16x8 c0 = cvt8(A0, A1), c1 = cvt8(B0, B1);
            *(bf16x8*)&zl[1 - p][srow * ZSTR + spr * 8] = c0;
            *(bf16x8*)&zl[1 - p][(16 + srow) * ZSTR + spr * 8] = c1;
            if (write_zb) {
                *(bf16x8*)(zb + (tok0 + (s + 1) * STRIP + srow) * EE + spr * 8) = c0;
                *(bf16x8*)(zb + (tok0 + (s + 1) * STRIP + 16 + srow) * EE + spr * 8) = c1;
            }
        }
        __syncthreads();   // zl[1-p] ready; all reads of zl[p] done (one barrier/strip)
    }

    // reduce over the 16 token-lanes (l16)
    for (int t = 0; t < 2; ++t)
        for (int off = 1; off < 16; off <<= 1)
            for (int r = 0; r < 4; ++r)
                rmax[t][r] = fmaxf(rmax[t][r], __shfl_xor(rmax[t][r], off, 64));
    if (l16 == 0) {
        for (int t = 0; t < 2; ++t) {
            float4 o; o.x = rmax[t][0]; o.y = rmax[t][1]; o.z = rmax[t][2]; o.w = rmax[t][3];
            *(float4*)(part + (size_t)blk * EE + w * 32 + t * 16 + q * 4) = o;
        }
    }
}

// ---------------------------------------------------------------------------
// Phase 1b: reduce partials over chunks, add M2 bias. grid = B, block = 128.
// ---------------------------------------------------------------------------
__global__ void pool_reduce(const float* __restrict__ part,
                            const float* __restrict__ M2b,
                            float* __restrict__ pooled) {
    const int b = blockIdx.x, f = threadIdx.x;
    float m = -3.0e38f;
    for (int ch = 0; ch < CH; ++ch)
        m = fmaxf(m, part[((size_t)(b * CH + ch)) * EE + f]);
    pooled[b * EE + f] = m + M2b[f];
}

// ---------------------------------------------------------------------------
// Phase 2: out = relu([z | relu(z@M1^T + b1 + pooled)] @ U^T + bU)
// 1024 blocks x 256 threads, 4 waves, 2 h-tiles/wave. One barrier per strip:
//   phase1: read zl[p] -> M1 MFMA + U-low MFMA, write ml[p]
//   stage zl[1-p]; BARRIER; phase2: read ml[p] -> U-high MFMA, store out.
// Hazards: zl[1-p] write < barrier < next-strip zl[1-p] reads; all zl[p] reads
// are pre-barrier, next strip writes zl[p] post-barrier; ml buffers alternate.
// ---------------------------------------------------------------------------
__global__ __launch_bounds__(256, 3)
void fused_main(const float* __restrict__ z, const unsigned short* __restrict__ zb,
                int use_zb,
                const float* __restrict__ M1w, const float* __restrict__ M1b,
                const float* __restrict__ Uw,  const float* __restrict__ Ub,
                const float* __restrict__ pooled, float* __restrict__ out) {
    __shared__ __attribute__((aligned(16))) unsigned short zl[2][STRIP * ZSTR];
    __shared__ __attribute__((aligned(16))) unsigned short ml[2][STRIP * ZSTR];

    const int tid  = threadIdx.x;
    const int w    = tid >> 6, lane = tid & 63, q = lane >> 4, l16 = lane & 15;
    const int blk  = blockIdx.x;
    const int b    = blk >> 5, ch = blk & (CH - 1);
    const long tok0 = (long)b * KK + (long)ch * TPB;

    // bf16 staging map (2 x 16B per thread); fp32 fallback map (4 x float4)
    const int brow = tid >> 4, bsl = tid & 15;      // bf16: rows brow, brow+16

    // weights: wave owns h/f range w*32 .. w*32+31
    bf16x8 wf1[2][4];
    bf16x8 wfu[2][8];
    float4 bp[2], ub[2];
    for (int t = 0; t < 2; ++t) {
        const int row = w * 32 + t * 16 + l16;
        for (int k = 0; k < 4; ++k)
            wf1[t][k] = load8_bf16(M1w + row * EE + k * 32 + q * 8);
        for (int kk = 0; kk < 8; ++kk)
            wfu[t][kk] = load8_bf16(Uw + row * (2 * EE) + kk * 32 + q * 8);
        const float4 mb = *(const float4*)(M1b + w * 32 + t * 16 + q * 4);
        const float4 pl = *(const float4*)(pooled + b * EE + w * 32 + t * 16 + q * 4);
        bp[t].x = mb.x + pl.x; bp[t].y = mb.y + pl.y;
        bp[t].z = mb.z + pl.z; bp[t].w = mb.w + pl.w;
        ub[t] = *(const float4*)(Ub + w * 32 + t * 16 + q * 4);
    }

    // stage strip 0
    if (use_zb) {
        *(bf16x8*)&zl[0][brow * ZSTR + bsl * 8] =
            *(const bf16x8*)(zb + (tok0 + brow) * EE + bsl * 8);
        *(bf16x8*)&zl[0][(16 + brow) * ZSTR + bsl * 8] =
            *(const bf16x8*)(zb + (tok0 + 16 + brow) * EE + bsl * 8);
    } else {
        const float* r0 = z + (tok0 + brow) * EE + bsl * 8;
        const float* r1 = z + (tok0 + 16 + brow) * EE + bsl * 8;
        *(bf16x8*)&zl[0][brow * ZSTR + bsl * 8] =
            cvt8(((const float4*)r0)[0], ((const float4*)r0)[1]);
        *(bf16x8*)&zl[0][(16 + brow) * ZSTR + bsl * 8] =
            cvt8(((const float4*)r1)[0], ((const float4*)r1)[1]);
    }
    __syncthreads();

    for (int s = 0; s < NSTRIP; ++s) {
        const int p = s & 1;
        const bool pf = (s + 1 < NSTRIP);

        // prefetch strip s+1
        bf16x8 Rb[2];
        float4 F0, F1, F2, F3;
        if (pf) {
            if (use_zb) {
                Rb[0] = *(const bf16x8*)(zb + (tok0 + (s + 1) * STRIP + brow) * EE + bsl * 8);
                Rb[1] = *(const bf16x8*)(zb + (tok0 + (s + 1) * STRIP + 16 + brow) * EE + bsl * 8);
            } else {
                const float* r0 = z + (tok0 + (s + 1) * STRIP + brow) * EE + bsl * 8;
                const float* r1 = z + (tok0 + (s + 1) * STRIP + 16 + brow) * EE + bsl * 8;
                F0 = ((const float4*)r0)[0]; F1 = ((const float4*)r0)[1];
                F2 = ((const float4*)r1)[0]; F3 = ((const float4*)r1)[1];
            }
        }

        f32x4 accU[2][2] = {};   // [ts][t], persists across the barrier

        // phase 1: M1 + U-low from zl[p]; emit ml[p]
        for (int ts = 0; ts < 2; ++ts) {
            bf16x8 zf[4];
            for (int k = 0; k < 4; ++k)
                zf[k] = *(const bf16x8*)&zl[p][(ts * 16 + l16) * ZSTR + k * 32 + q * 8];
            f32x4 a1[2] = {};
            for (int k = 0; k < 4; ++k)
                for (int t = 0; t < 2; ++t) {
                    a1[t]       = __builtin_amdgcn_mfma_f32_16x16x32_bf16(wf1[t][k], zf[k], a1[t], 0, 0, 0);
                    accU[ts][t] = __builtin_amdgcn_mfma_f32_16x16x32_bf16(wfu[t][k], zf[k], accU[ts][t], 0, 0, 0);
                }
            for (int t = 0; t < 2; ++t) {
                ushort4 o;
                o.x = f2bf(fmaxf(a1[t][0] + bp[t].x, 0.f));
                o.y = f2bf(fmaxf(a1[t][1] + bp[t].y, 0.f));
                o.z = f2bf(fmaxf(a1[t][2] + bp[t].z, 0.f));
                o.w = f2bf(fmaxf(a1[t][3] + bp[t].w, 0.f));
                *(ushort4*)&ml[p][(ts * 16 + l16) * ZSTR + w * 32 + t * 16 + q * 4] = o;
            }
        }

        // stage next strip into zl[1-p] (pre-barrier — hazard-free, see header)
        if (pf) {
            bf16x8 c0, c1;
            if (use_zb) { c0 = Rb[0]; c1 = Rb[1]; }
            else        { c0 = cvt8(F0, F1); c1 = cvt8(F2, F3); }
            *(bf16x8*)&zl[1 - p][brow * ZSTR + bsl * 8] = c0;
            *(bf16x8*)&zl[1 - p][(16 + brow) * ZSTR + bsl * 8] = c1;
        }
        __syncthreads();

        // phase 2: U-high from ml[p]; store out
        for (int ts = 0; ts < 2; ++ts) {
            bf16x8 mf[4];
            for (int k = 0; k < 4; ++k)
                mf[k] = *(const bf16x8*)&ml[p][(ts * 16 + l16) * ZSTR + k * 32 + q * 8];
            for (int k = 0; k < 4; ++k)
                for (int t = 0; t < 2; ++t)
                    accU[ts][t] = __builtin_amdgcn_mfma_f32_16x16x32_bf16(wfu[t][4 + k], mf[k], accU[ts][t], 0, 0, 0);
            for (int t = 0; t < 2; ++t) {
                float4 o;
                o.x = fmaxf(accU[ts][t][0] + ub[t].x, 0.f);
                o.y = fmaxf(accU[ts][t][1] + ub[t].y, 0.f);
                o.z = fmaxf(accU[ts][t][2] + ub[t].z, 0.f);
                o.w = fmaxf(accU[ts][t][3] + ub[t].w, 0.f);
                *(float4*)(out + (tok0 + s * STRIP + ts * 16 + l16) * HH + w * 32 + t * 16 + q * 4) = o;
            }
        }
        // no second barrier: next strip's zl[p] staging writes are post-barrier
        // of THIS strip only after every wave passed it, and phase2 touches
        // only ml[p]/global. ml[1-p] writes (next strip) don't alias ml[p].
    }
}

// ---------------------------------------------------------------------------
extern "C" void kernel_launch(void* const* d_in, const int* in_sizes, int n_in,
                              void* d_out, int out_size, void* d_ws, size_t ws_size,
                              hipStream_t stream) {
    const float* z   = (const float*)d_in[0];
    const float* M1w = (const float*)d_in[1];
    const float* M1b = (const float*)d_in[2];
    const float* M2w = (const float*)d_in[3];
    const float* M2b = (const float*)d_in[4];
    const float* Uw  = (const float*)d_in[5];
    const float* Ub  = (const float*)d_in[6];
    float* out = (float*)d_out;

    // ws layout: part [B*CH*E] f32 | pooled [B*E] f32 | zb [B*K*E] bf16 (optional)
    float* part   = (float*)d_ws;
    float* pooled = part + (size_t)BB * CH * EE;
    unsigned short* zb = (unsigned short*)(pooled + BB * EE);
    const size_t head = (size_t)BB * CH * EE * 4 + (size_t)BB * EE * 4;
    const int use_zb = (ws_size >= head + (size_t)BB * KK * EE * 2) ? 1 : 0;

    hipLaunchKernelGGL(pool_partial, dim3(BB * CH), dim3(256), 0, stream,
                       z, M2w, part, zb, use_zb);
    hipLaunchKernelGGL(pool_reduce,  dim3(BB),      dim3(EE),  0, stream, part, M2b, pooled);
    hipLaunchKernelGGL(fused_main,   dim3(BB * CH), dim3(256), 0, stream,
                       z, zb, use_zb, M1w, M1b, Uw, Ub, pooled, out);
}

// Round 4
// 311.878 us; speedup vs baseline: 1.5336x; 1.3173x over previous
//
#include <hip/hip_runtime.h>

// Problem constants (fixed by the reference).
#define BB 32
#define KK 8192
#define EE 128
#define HH 128
#define CH 32                     // chunks per batch -> 1024 blocks
#define TPB (KK / CH)             // 256 tokens per block
#define STRIP 32                  // tokens per LDS strip
#define NSTRIP (TPB / STRIP)      // 8
#define ZSTR 136                  // LDS row stride in shorts (272 B)

typedef short bf16x8 __attribute__((ext_vector_type(8)));
typedef float f32x4  __attribute__((ext_vector_type(4)));

static __device__ __forceinline__ unsigned short f2bf(float x) {
    union { float f; unsigned u; } v; v.f = x;
    unsigned u = v.u;
    u += 0x7FFFu + ((u >> 16) & 1u);   // RNE
    return (unsigned short)(u >> 16);
}

static __device__ __forceinline__ bf16x8 cvt8(float4 a, float4 b) {
    bf16x8 r;
    r[0] = (short)f2bf(a.x); r[1] = (short)f2bf(a.y);
    r[2] = (short)f2bf(a.z); r[3] = (short)f2bf(a.w);
    r[4] = (short)f2bf(b.x); r[5] = (short)f2bf(b.y);
    r[6] = (short)f2bf(b.z); r[7] = (short)f2bf(b.w);
    return r;
}

// ---------------------------------------------------------------------------
// Prologue: pack M1/M2/U fp32 row-major weights into bf16 MFMA A-fragments,
// fragment-linear: frag(tile,k) occupies 64 lanes x 16 B, lane-contiguous.
// Element for lane (q=lane>>4, l16=lane&15): row = tile*16+l16, col = k*32+q*8.
// 8192 threads total (32 blocks x 256).
// ---------------------------------------------------------------------------
__global__ void prepack(const float* __restrict__ M1w, const float* __restrict__ M2w,
                        const float* __restrict__ Uw,
                        unsigned short* __restrict__ w1p,
                        unsigned short* __restrict__ w2p,
                        unsigned short* __restrict__ wup) {
    const int id   = blockIdx.x * 256 + threadIdx.x;   // 0..8191
    const int lane = id & 63, fid = id >> 6;
    const int q = lane >> 4, l16 = lane & 15;
    const float* src;
    unsigned short* dst;
    if (fid < 32) {               // M1: tile=fid>>2, k=fid&3
        src = M1w + ((fid >> 2) * 16 + l16) * EE + (fid & 3) * 32 + q * 8;
        dst = w1p + (size_t)(fid * 64 + lane) * 8;
    } else if (fid < 64) {        // M2
        const int f = fid - 32;
        src = M2w + ((f >> 2) * 16 + l16) * EE + (f & 3) * 32 + q * 8;
        dst = w2p + (size_t)(f * 64 + lane) * 8;
    } else {                      // U: tile=(fid-64)>>3, kk=(fid-64)&7, 256 cols
        const int f = fid - 64;
        src = Uw + ((f >> 3) * 16 + l16) * (2 * EE) + (f & 7) * 32 + q * 8;
        dst = wup + (size_t)(f * 64 + lane) * 8;
    }
    *(bf16x8*)dst = cvt8(((const float4*)src)[0], ((const float4*)src)[1]);
}

// ---------------------------------------------------------------------------
// Phase 1: partial column-max of z @ M2^T; emits z as bf16 (zb) if ws allows.
// 1024 blocks x 512 threads (8 waves, 1 16-feature tile each).
// LDS: double-buffered z strip (bf16, token-major). One barrier per strip.
// ---------------------------------------------------------------------------
__global__ __launch_bounds__(512) __attribute__((amdgpu_waves_per_eu(4, 4)))
void pool_partial(const float* __restrict__ z, const unsigned short* __restrict__ w2p,
                  float* __restrict__ part, unsigned short* __restrict__ zb,
                  int write_zb) {
    __shared__ __attribute__((aligned(16))) unsigned short zl[2][STRIP * ZSTR];

    const int tid  = threadIdx.x;
    const int w    = tid >> 6, lane = tid & 63, q = lane >> 4, l16 = lane & 15;
    const int blk  = blockIdx.x;
    const int b    = blk >> 5, ch = blk & (CH - 1);
    const long tok0 = (long)b * KK + (long)ch * TPB;

    // staging: thread covers token row sr (0..31), 8-elem group sg (0..15)
    const int sr = tid >> 4, sg = tid & 15;

    // resident M2 tile fragments (wave w -> features w*16..w*16+15): 16 VGPR
    bf16x8 wf[4];
    for (int k = 0; k < 4; ++k)
        wf[k] = *(const bf16x8*)(w2p + (size_t)((w * 4 + k) * 64 + lane) * 8);

    // stage strip 0
    {
        const float* r = z + (tok0 + sr) * EE + sg * 8;
        const bf16x8 c = cvt8(((const float4*)r)[0], ((const float4*)r)[1]);
        *(bf16x8*)&zl[0][sr * ZSTR + sg * 8] = c;
        if (write_zb) *(bf16x8*)(zb + (tok0 + sr) * EE + sg * 8) = c;
    }
    __syncthreads();

    f32x4 rmax[2];
    for (int t = 0; t < 2; ++t)
        for (int r = 0; r < 4; ++r) rmax[t][r] = -3.0e38f;

    for (int s = 0; s < NSTRIP; ++s) {
        const int p = s & 1;
        const bool pf = (s + 1 < NSTRIP);
        float4 A0, A1;
        if (pf) {
            const float* r = z + (tok0 + (s + 1) * STRIP + sr) * EE + sg * 8;
            A0 = ((const float4*)r)[0]; A1 = ((const float4*)r)[1];
        }

        for (int ts = 0; ts < 2; ++ts) {
            bf16x8 zf[4];
            for (int k = 0; k < 4; ++k)
                zf[k] = *(const bf16x8*)&zl[p][(ts * 16 + l16) * ZSTR + k * 32 + q * 8];
            f32x4 acc = {0.f, 0.f, 0.f, 0.f};
            for (int k = 0; k < 4; ++k)
                acc = __builtin_amdgcn_mfma_f32_16x16x32_bf16(wf[k], zf[k], acc, 0, 0, 0);
            for (int r = 0; r < 4; ++r)
                rmax[ts][r] = fmaxf(rmax[ts][r], acc[r]);
        }

        if (pf) {
            const bf16x8 c = cvt8(A0, A1);
            *(bf16x8*)&zl[1 - p][sr * ZSTR + sg * 8] = c;
            if (write_zb) *(bf16x8*)(zb + (tok0 + (s + 1) * STRIP + sr) * EE + sg * 8) = c;
        }
        __syncthreads();   // zl[1-p] ready; all reads of zl[p] done
    }

    f32x4 rm;
    for (int r = 0; r < 4; ++r) rm[r] = fmaxf(rmax[0][r], rmax[1][r]);
    for (int off = 1; off < 16; off <<= 1)
        for (int r = 0; r < 4; ++r)
            rm[r] = fmaxf(rm[r], __shfl_xor(rm[r], off, 64));
    if (l16 == 0) {
        float4 o; o.x = rm[0]; o.y = rm[1]; o.z = rm[2]; o.w = rm[3];
        *(float4*)(part + (size_t)blk * EE + w * 16 + q * 4) = o;
    }
}

// ---------------------------------------------------------------------------
// Phase 1b: reduce partials over chunks, add M2 bias. grid = B, block = 128.
// ---------------------------------------------------------------------------
__global__ void pool_reduce(const float* __restrict__ part,
                            const float* __restrict__ M2b,
                            float* __restrict__ pooled) {
    const int b = blockIdx.x, f = threadIdx.x;
    float m = -3.0e38f;
    for (int ch = 0; ch < CH; ++ch)
        m = fmaxf(m, part[((size_t)(b * CH + ch)) * EE + f]);
    pooled[b * EE + f] = m + M2b[f];
}

// ---------------------------------------------------------------------------
// Phase 2: out = relu([z | relu(z@M1^T + b1 + pooled)] @ U^T + bU)
// 1024 blocks x 512 threads (8 waves, 1 16-h tile each).
// z fragments come straight from global (zb bf16, or fp32 fallback) — no zl.
// LDS: only the double-buffered ml tile (17 KB). One barrier per strip:
//   ph1: zf (global) -> M1 + U-low MFMA -> write ml[p]; BARRIER;
//   ph2: mf (ds_read ml[p]) -> U-high MFMA -> float4 out stores.
// Buffer safety: strip s+2 rewrites ml[p] only after s+1's barrier, which
// every wave reaches only after finishing s's ph2 reads of ml[p].
// ---------------------------------------------------------------------------
__global__ __launch_bounds__(512) __attribute__((amdgpu_waves_per_eu(4, 4)))
void fused_main(const float* __restrict__ z, const unsigned short* __restrict__ zb,
                int use_zb,
                const unsigned short* __restrict__ w1p,
                const unsigned short* __restrict__ wup,
                const float* __restrict__ M1b, const float* __restrict__ Ub,
                const float* __restrict__ pooled, float* __restrict__ out) {
    __shared__ __attribute__((aligned(16))) unsigned short ml[2][STRIP * ZSTR];

    const int tid  = threadIdx.x;
    const int w    = tid >> 6, lane = tid & 63, q = lane >> 4, l16 = lane & 15;
    const int blk  = blockIdx.x;
    const int b    = blk >> 5, ch = blk & (CH - 1);
    const long tok0 = (long)b * KK + (long)ch * TPB;

    // resident weights: M1 tile (16 VGPR) + U tile over K=256 (32 VGPR)
    bf16x8 wf1[4];
    for (int k = 0; k < 4; ++k)
        wf1[k] = *(const bf16x8*)(w1p + (size_t)((w * 4 + k) * 64 + lane) * 8);
    bf16x8 wfu[8];
    for (int kk = 0; kk < 8; ++kk)
        wfu[kk] = *(const bf16x8*)(wup + (size_t)((w * 8 + kk) * 64 + lane) * 8);

    const float4 mb = *(const float4*)(M1b + w * 16 + q * 4);
    const float4 pl = *(const float4*)(pooled + b * EE + w * 16 + q * 4);
    float4 bp; bp.x = mb.x + pl.x; bp.y = mb.y + pl.y;
               bp.z = mb.z + pl.z; bp.w = mb.w + pl.w;
    const float4 ub = *(const float4*)(Ub + w * 16 + q * 4);

    for (int s = 0; s < NSTRIP; ++s) {
        const int p = s & 1;
        const long trow = tok0 + s * STRIP;

        // ph1: load all 8 z fragments (global), M1 + U-low, emit ml[p]
        bf16x8 zf[2][4];
        if (use_zb) {
            for (int ts = 0; ts < 2; ++ts)
                for (int k = 0; k < 4; ++k)
                    zf[ts][k] = *(const bf16x8*)(zb + (trow + ts * 16 + l16) * EE + k * 32 + q * 8);
        } else {
            for (int ts = 0; ts < 2; ++ts)
                for (int k = 0; k < 4; ++k) {
                    const float* r = z + (trow + ts * 16 + l16) * EE + k * 32 + q * 8;
                    zf[ts][k] = cvt8(((const float4*)r)[0], ((const float4*)r)[1]);
                }
        }

        f32x4 accU[2] = {};
        for (int ts = 0; ts < 2; ++ts) {
            f32x4 a1 = {0.f, 0.f, 0.f, 0.f};
            for (int k = 0; k < 4; ++k) {
                a1       = __builtin_amdgcn_mfma_f32_16x16x32_bf16(wf1[k], zf[ts][k], a1, 0, 0, 0);
                accU[ts] = __builtin_amdgcn_mfma_f32_16x16x32_bf16(wfu[k], zf[ts][k], accU[ts], 0, 0, 0);
            }
            ushort4 o;
            o.x = f2bf(fmaxf(a1[0] + bp.x, 0.f));
            o.y = f2bf(fmaxf(a1[1] + bp.y, 0.f));
            o.z = f2bf(fmaxf(a1[2] + bp.z, 0.f));
            o.w = f2bf(fmaxf(a1[3] + bp.w, 0.f));
            *(ushort4*)&ml[p][(ts * 16 + l16) * ZSTR + w * 16 + q * 4] = o;
        }
        __syncthreads();   // ml[p] complete

        // ph2: U-high from ml[p], store out
        for (int ts = 0; ts < 2; ++ts) {
            bf16x8 mf[4];
            for (int k = 0; k < 4; ++k)
                mf[k] = *(const bf16x8*)&ml[p][(ts * 16 + l16) * ZSTR + k * 32 + q * 8];
            for (int k = 0; k < 4; ++k)
                accU[ts] = __builtin_amdgcn_mfma_f32_16x16x32_bf16(wfu[4 + k], mf[k], accU[ts], 0, 0, 0);
            float4 o;
            o.x = fmaxf(accU[ts][0] + ub.x, 0.f);
            o.y = fmaxf(accU[ts][1] + ub.y, 0.f);
            o.z = fmaxf(accU[ts][2] + ub.z, 0.f);
            o.w = fmaxf(accU[ts][3] + ub.w, 0.f);
            *(float4*)(out + (trow + ts * 16 + l16) * HH + w * 16 + q * 4) = o;
        }
    }
}

// ---------------------------------------------------------------------------
extern "C" void kernel_launch(void* const* d_in, const int* in_sizes, int n_in,
                              void* d_out, int out_size, void* d_ws, size_t ws_size,
                              hipStream_t stream) {
    const float* z   = (const float*)d_in[0];
    const float* M1w = (const float*)d_in[1];
    const float* M1b = (const float*)d_in[2];
    const float* M2w = (const float*)d_in[3];
    const float* M2b = (const float*)d_in[4];
    const float* Uw  = (const float*)d_in[5];
    const float* Ub  = (const float*)d_in[6];
    float* out = (float*)d_out;

    // ws: w1p 32K | w2p 32K | wup 64K | part 512K | pooled 16K | zb 64M (opt)
    unsigned short* w1p = (unsigned short*)d_ws;
    unsigned short* w2p = w1p + 16384;
    unsigned short* wup = w2p + 16384;
    float* part   = (float*)(wup + 32768);
    float* pooled = part + (size_t)BB * CH * EE;
    unsigned short* zb = (unsigned short*)(pooled + BB * EE);
    const size_t head = 2 * 16384 * 2 + 32768 * 2 + (size_t)BB * CH * EE * 4 + (size_t)BB * EE * 4;
    const int use_zb = (ws_size >= head + (size_t)BB * KK * EE * 2) ? 1 : 0;

    hipLaunchKernelGGL(prepack,      dim3(32),      dim3(256), 0, stream,
                       M1w, M2w, Uw, w1p, w2p, wup);
    hipLaunchKernelGGL(pool_partial, dim3(BB * CH), dim3(512), 0, stream,
                       z, w2p, part, zb, use_zb);
    hipLaunchKernelGGL(pool_reduce,  dim3(BB),      dim3(EE),  0, stream, part, M2b, pooled);
    hipLaunchKernelGGL(fused_main,   dim3(BB * CH), dim3(512), 0, stream,
                       z, zb, use_zb, w1p, wup, M1b, Ub, pooled, out);
}